// Round 10
// baseline (530.115 us; speedup 1.0000x reference)
//
#include <hip/hip_runtime.h>

typedef __attribute__((ext_vector_type(4))) float    f32x4;
typedef __attribute__((ext_vector_type(4))) short    s16x4;
typedef __attribute__((ext_vector_type(8))) short    s16x8;
typedef __attribute__((ext_vector_type(8))) _Float16 h16x8;

#define XS_STRIDE 520   // 512 + 8 bf16 pad
#define ROWS_BLK 32     // rows per iteration per block
#define NITER 4         // 1024 row-blocks / 256 blocks

__device__ __forceinline__ short f2bf(float f) {
  unsigned u = __float_as_uint(f);
  u = (u + 0x7fffu + ((u >> 16) & 1u)) >> 16;   // RNE
  return (short)u;
}

// ---------------- precompute (unchanged from round 6) ----------------
// wF[d2][vt][kt][lane][j] = lin_w[d2][k][v] / sqrt(128), bf16
// cc: per-v rows of 768 B (16 ab-groups x 48 B), fp16, XOR swizzle byte^=(v&7)<<4 baked in
// cu1[v][a*4+i] (f32)
__global__ void precompute_kernel(const float* __restrict__ lin_w,
                                  const float* __restrict__ w1,
                                  const float* __restrict__ w2,
                                  const float* __restrict__ w3,
                                  const float* __restrict__ C1,
                                  const float* __restrict__ C2,
                                  const float* __restrict__ C3,
                                  short*    __restrict__ wF,
                                  _Float16* __restrict__ cc,
                                  float*    __restrict__ cu1) {
  int tid = blockIdx.x * blockDim.x + threadIdx.x;
  int nth = gridDim.x * blockDim.x;
  const float rs = 0.088388347648318447f;  // 1/sqrt(128)
  for (int idx = tid; idx < 6 * 8 * 4 * 64 * 8; idx += nth) {
    int j  = idx & 7;
    int ln = (idx >> 3) & 63;
    int kt = (idx >> 9) & 3;
    int vt = (idx >> 11) & 7;
    int d2 = idx >> 14;
    int v  = vt * 16 + (ln & 15);
    int k  = kt * 32 + (ln >> 4) * 8 + j;
    wF[idx] = f2bf(lin_w[(d2 * 128 + k) * 128 + v] * rs);
  }
  for (int idx = tid; idx < 128 * 16 * 20; idx += nth) {
    int v  = idx / 320;
    int r  = idx - v * 320;
    int ab = r / 20;
    int j  = r - ab * 20;
    int a = ab >> 2, b = ab & 3;
    float s = 0.f;
    if (j < 16) {
      int c = j >> 2, i = j & 3;
      const float* p = C3 + (((a * 4 + b) * 4 + c) * 4 + i) * 12;
      #pragma unroll
      for (int w = 0; w < 12; ++w) s += p[w] * w3[w * 128 + v];
    } else {
      int i = j - 16;
      const float* p = C2 + ((a * 4 + b) * 4 + i) * 5;
      #pragma unroll
      for (int w = 0; w < 5; ++w) s += p[w] * w2[w * 128 + v];
    }
    int byte_in_row = (ab * 48 + j * 2) ^ ((v & 7) << 4);   // swizzle baked in
    cc[v * 384 + (byte_in_row >> 1)] = (_Float16)s;
  }
  for (int idx = tid; idx < 128 * 16; idx += nth) {
    int v = idx >> 4;
    int ai = idx & 15;
    int a = ai >> 2, i = ai & 3;
    cu1[idx] = C1[(a * 4 + i) * 2 + 0] * w1[v] + C1[(a * 4 + i) * 2 + 1] * w1[128 + v];
  }
}

// ---------------- persistent fused main: 1024 threads, 4 waves/SIMD ----------------
// 256 blocks x 1024 threads (16 waves: rt = wave>>3 row-tile, vt = wave&7) x 4 iters
// of 32 rows. LDS: xs 33,280 + cc 98,304 + cu1 8,192 = 139,776 B -> 1 block/CU,
// 16 waves/CU = 4 waves/SIMD (was 2). To fit the 128-VGPR cap 16 waves require,
// wF is streamed per-d2 (TLP now hides its L2 latency) and cu1 lives in LDS.
// Phase order keeps round-8's drain-hiding: stores issue AFTER barB and drain at
// the next iteration's barA, under the whole MFMA phase.
__launch_bounds__(1024, 4)
__global__ void main_kernel(const float* __restrict__ x,
                            const short* __restrict__ wF,
                            const _Float16* __restrict__ cc,
                            const float* __restrict__ cu1,
                            float* __restrict__ out) {
  __shared__ short xs[ROWS_BLK * XS_STRIDE];       // 33,280 B (single buffer)
  __shared__ __align__(16) char  ccl[98304];       // swizzled cc table
  __shared__ __align__(16) float cul[2048];        // cu1 table (8,192 B)

  const int t    = threadIdx.x;   // 0..1023
  const int lane = t & 63;
  const int wave = t >> 6;        // 0..15
  const int rt   = wave >> 3;     // 0..1 row-tile
  const int vt   = wave & 7;      // 0..7
  const int vl   = lane & 15;
  const int quad = lane >> 4;     // 0..3
  const int b    = blockIdx.x;    // 0..255
  const int v    = vt * 16 + vl;

  // ---- prologue: cc->LDS, cu1->LDS, x iter0 -> xs ----
  {
    const f32x4* csrc = (const f32x4*)cc;
    f32x4*       cdst = (f32x4*)ccl;
    #pragma unroll
    for (int i = 0; i < 6; ++i) cdst[i * 1024 + t] = csrc[i * 1024 + t];
  }
  if (t < 512) ((f32x4*)cul)[t] = ((const f32x4*)cu1)[t];
  {
    const float4* xsrc = (const float4*)(x + (size_t)b * ROWS_BLK * 512);
    #pragma unroll
    for (int i2 = 0; i2 < 4; ++i2) {
      int f = i2 * 1024 + t;             // float4 id, 0..4095 (32 rows x 128)
      float4 xv = xsrc[f];
      int row = f >> 7, c4 = f & 127;
      s16x4 pk;
      pk[0] = f2bf(xv.x); pk[1] = f2bf(xv.y); pk[2] = f2bf(xv.z); pk[3] = f2bf(xv.w);
      *(s16x4*)&xs[row * XS_STRIDE + c4 * 4] = pk;
    }
  }
  __syncthreads();

  float4 xq[4];
  #pragma unroll 1
  for (int k = 0; k < NITER; ++k) {
    const int n0 = (k * 256 + b) * ROWS_BLK + rt * 16;

    // ---- MFMA phase: wF streamed per-d2 (4-wave TLP hides L2 latency) ----
    float yreg[12][4];
    #pragma unroll
    for (int d2 = 0; d2 < 6; ++d2) {
      s16x8 bf[4];
      {
        const s16x8* wsrc = (const s16x8*)wF + (d2 * 8 + vt) * 256 + lane;
        #pragma unroll
        for (int kt = 0; kt < 4; ++kt) bf[kt] = wsrc[kt * 64];
      }
      const int d = d2 >> 1, blk = d2 & 1;
      const int a_begin = blk ? 1 : 0;
      const int a_end   = blk ? 4 : 1;
      #pragma unroll
      for (int a = a_begin; a < a_end; ++a) {
        f32x4 acc4 = {0.f, 0.f, 0.f, 0.f};
        #pragma unroll
        for (int kt = 0; kt < 4; ++kt) {
          s16x8 af = *(const s16x8*)&xs[(rt * 16 + vl) * XS_STRIDE + a * 128 + kt * 32 + quad * 8];
          acc4 = __builtin_amdgcn_mfma_f32_16x16x32_bf16(af, bf[kt], acc4, 0, 0, 0);
        }
        const int da = d * 4 + a;
        #pragma unroll
        for (int r = 0; r < 4; ++r) yreg[da][r] = acc4[r];
      }
    }

    __syncthreads();   // bar A: all xs reads done; prior-iter stores drain here (hidden)

    // issue next x tile's global loads (land during the contraction)
    if (k + 1 < NITER) {
      const float4* xsrc = (const float4*)(x + (size_t)((k + 1) * 256 + b) * ROWS_BLK * 512);
      #pragma unroll
      for (int i2 = 0; i2 < 4; ++i2) xq[i2] = xsrc[i2 * 1024 + t];
    }
    __builtin_amdgcn_sched_barrier(0);

    // ---- contraction (fp32 math, fp16 coeffs from swizzled LDS, cu1 from LDS) ----
    float acc[4][4];   // [i][r]
    {
      const f32x4* c1p = (const f32x4*)(cul + v * 16);
      float c1[16];
      #pragma unroll
      for (int q = 0; q < 4; ++q) {
        f32x4 tv = c1p[q];
        c1[4 * q + 0] = tv[0]; c1[4 * q + 1] = tv[1];
        c1[4 * q + 2] = tv[2]; c1[4 * q + 3] = tv[3];
      }
      #pragma unroll
      for (int i = 0; i < 4; ++i)
        #pragma unroll
        for (int r = 0; r < 4; ++r) {
          float s = c1[0 * 4 + i] * yreg[0][r];
          s = fmaf(c1[1 * 4 + i], yreg[1][r], s);
          s = fmaf(c1[2 * 4 + i], yreg[2][r], s);
          s = fmaf(c1[3 * 4 + i], yreg[3][r], s);
          acc[i][r] = s;
        }
    }

    const char* myc = ccl + v * 768;
    const int   vm  = (v & 7) << 4;
    #pragma unroll
    for (int ab = 0; ab < 16; ++ab) {
      h16x8 h0 = *(const h16x8*)(myc + ((ab * 48 +  0) ^ vm));
      h16x8 h1 = *(const h16x8*)(myc + ((ab * 48 + 16) ^ vm));
      h16x8 h2 = *(const h16x8*)(myc + ((ab * 48 + 32) ^ vm));
      const int a = ab >> 2, b2 = ab & 3;
      float cj[20];
      #pragma unroll
      for (int j = 0; j < 8; ++j) { cj[j] = (float)h0[j]; cj[8 + j] = (float)h1[j]; }
      #pragma unroll
      for (int j = 0; j < 4; ++j) cj[16 + j] = (float)h2[j];
      #pragma unroll
      for (int r = 0; r < 4; ++r) {
        const float G = yreg[a][r] * yreg[4 + b2][r];
        #pragma unroll
        for (int i = 0; i < 4; ++i) {
          float s = cj[16 + i];
          s = fmaf(cj[0 + i],  yreg[8][r],  s);
          s = fmaf(cj[4 + i],  yreg[9][r],  s);
          s = fmaf(cj[8 + i],  yreg[10][r], s);
          s = fmaf(cj[12 + i], yreg[11][r], s);
          acc[i][r] = fmaf(G, s, acc[i][r]);
        }
      }
    }

    // write next tile into xs (xq loads had the whole contraction to land)
    if (k + 1 < NITER) {
      #pragma unroll
      for (int i2 = 0; i2 < 4; ++i2) {
        int f = i2 * 1024 + t;
        int row = f >> 7, c4 = f & 127;
        s16x4 pk;
        pk[0] = f2bf(xq[i2].x); pk[1] = f2bf(xq[i2].y);
        pk[2] = f2bf(xq[i2].z); pk[3] = f2bf(xq[i2].w);
        *(s16x4*)&xs[row * XS_STRIDE + c4 * 4] = pk;
      }
      __syncthreads();   // bar B: xs staged for iter k+1
    }

    // stores for iter k: issued after barB, drain at next iter's barA (hidden)
    #pragma unroll
    for (int r = 0; r < 4; ++r) {
      const int n = n0 + quad * 4 + r;
      #pragma unroll
      for (int i = 0; i < 4; ++i) out[(size_t)n * 512 + i * 128 + v] = acc[i][r];
    }
  }
}

extern "C" void kernel_launch(void* const* d_in, const int* in_sizes, int n_in,
                              void* d_out, int out_size, void* d_ws, size_t ws_size,
                              hipStream_t stream) {
  const float* x     = (const float*)d_in[0];
  const float* lin_w = (const float*)d_in[1];
  const float* w1    = (const float*)d_in[2];
  const float* w2    = (const float*)d_in[3];
  const float* w3    = (const float*)d_in[4];
  const float* C1    = (const float*)d_in[5];
  const float* C2    = (const float*)d_in[6];
  const float* C3    = (const float*)d_in[7];

  char* ws = (char*)d_ws;
  short*    wF  = (short*)ws;                     // 196608 B
  _Float16* cc  = (_Float16*)(ws + 196608);       //  98304 B (swizzled layout)
  float*    cu1 = (float*)(ws + 294912);          //   8192 B
  float*    out = (float*)d_out;

  hipLaunchKernelGGL(precompute_kernel, dim3(384), dim3(256), 0, stream,
                     lin_w, w1, w2, w3, C1, C2, C3, wF, cc, cu1);
  hipLaunchKernelGGL(main_kernel, dim3(256), dim3(1024), 0, stream,
                     x, wF, cc, cu1, out);
}